// Round 2
// baseline (49.562 us; speedup 1.0000x reference)
//
#include <hip/hip_runtime.h>

#define DT   0.1f
#define DT2  0.01f
#define DT3  0.001f

// ---------------------------------------------------------------------------
// The LQR decouples per axis into a 3-state (p,v,a | jerk) problem; axes 0,1
// share weights (type 0), axis 2 = yaw (type 1). The entire backward+forward
// pipeline is LINEAR in (x_init, targets) with batch-independent operators:
//   plan[b,t,a] = sum_s H_ty[t][s] * tgt[b,s,a] + sum_j G_ty[t][j] * x0_j[b,a]
// Kernel 1 builds H^T (2 x 80 x 80, [ty][s][t]) and G^T (2 x 3 x 80) in d_ws.
// Kernel 2 applies them as a small GEMM with full coalescing / LDS broadcast.
// ---------------------------------------------------------------------------

struct TB { float Qxu0, Qxu1, Qxu2, m; };

// One Riccati table step (V is symmetric, stored as 6 floats, updated in place)
__device__ inline TB table_step(float on, float cxp, float cxv,
                                float& v00, float& v01, float& v02,
                                float& v11, float& v12, float& v22) {
    const float b0 = DT3, b1 = DT2, b2 = DT;
    float Vb0 = v00*b0 + v01*b1 + v02*b2;
    float Vb1 = v01*b0 + v11*b1 + v12*b2;
    float Vb2 = v02*b0 + v12*b1 + v22*b2;
    float Quu = on*0.1f + b0*Vb0 + b1*Vb1 + b2*Vb2;
    float Qxu0 = Vb0;
    float Qxu1 = fmaf(DT,  Vb0, Vb1);
    float Qxu2 = fmaf(DT2, Vb0, fmaf(DT, Vb1, Vb2));
    float M01 = fmaf(DT,  v00, v01);
    float M02 = fmaf(DT2, v00, fmaf(DT, v01, v02));
    float M11 = fmaf(DT,  v01, v11);
    float M12 = fmaf(DT2, v01, fmaf(DT, v11, v12));
    float M22 = fmaf(DT2, v02, fmaf(DT, v12, v22));
    float Q00 = on*cxp + v00;
    float Q01 = M01;
    float Q02 = M02;
    float Q11 = on*cxv + fmaf(DT, M01, M11);
    float Q12 = fmaf(DT, M02, M12);
    float Q22 = on*1.0f + fmaf(DT2, M02, fmaf(DT, M12, M22));
    float m = -1.f / Quu;
    v00 = fmaf(m*Qxu0, Qxu0, Q00);
    v01 = fmaf(m*Qxu0, Qxu1, Q01);
    v02 = fmaf(m*Qxu0, Qxu2, Q02);
    v11 = fmaf(m*Qxu1, Qxu1, Q11);
    v12 = fmaf(m*Qxu1, Qxu2, Q12);
    v22 = fmaf(m*Qxu2, Qxu2, Q22);
    return {Qxu0, Qxu1, Qxu2, m};
}

// ---------------------------------------------------------------------------
// Kernel 1: impulse-response basis. Threads 0..159: (type, target column s*).
// Threads 160..165: (type, x0 component j). One block; ~160 serial steps each.
// ws layout (floats): [0..6400)   HT type0 [s][t]
//                     [6400..12800) HT type1
//                     [12800..13280) GT [ty*3+j][t]
// ---------------------------------------------------------------------------
__global__ __launch_bounds__(192) void lqr_basis_kernel(float* __restrict__ ws) {
    __shared__ float  ks[80 * 160];     // k_t per column thread, 51200 B
    __shared__ float4 ktbl[2][81];      // K gains (shared), 2592 B
    const int tid = threadIdx.x;
    const bool isCol = tid < 160;

    if (isCol) {
        const int ty = tid / 80, sc = tid % 80;
        const float cxp = ty ? 10.f : 1.f;
        const float cxv = ty ? 1.f : 0.f;
        const float w   = ty ? 10.f : 1.f;
        float v00=0.f,v01=0.f,v02=0.f,v11=0.f,v12=0.f,v22=0.f;
        float v0=0.f, v1=0.f, v2=0.f;     // linear term response
        for (int t = 80; t >= 1; --t) {
            TB tb = table_step(1.f, cxp, cxv, v00,v01,v02,v11,v12,v22);
            if (sc == 0)
                ktbl[ty][t] = make_float4(tb.Qxu0*tb.m, tb.Qxu1*tb.m, tb.Qxu2*tb.m, 0.f);
            float c  = (t-1 == sc) ? -w : 0.f;   // unit target impulse at s*=t-1
            float a1 = fmaf(DT, v0, v1);
            float a2 = fmaf(DT, a1, v2);
            float k  = DT * a2 * tb.m;           // k_t
            if (t <= 79) ks[t*160 + tid] = k;    // k_80 unused by forward pass
            v0 = (c + v0) + tb.Qxu0 * k;
            v1 = a1 + tb.Qxu1 * k;
            v2 = a2 + tb.Qxu2 * k;
        }
        TB tb0 = table_step(0.f, cxp, cxv, v00,v01,v02,v11,v12,v22); // t=0: C==0
        if (sc == 0)
            ktbl[ty][0] = make_float4(tb0.Qxu0*tb0.m, tb0.Qxu1*tb0.m, tb0.Qxu2*tb0.m, 0.f);
        float a1 = fmaf(DT, v0, v1);
        float a2 = fmaf(DT, a1, v2);
        ks[tid] = DT * a2 * tb0.m;               // k_0
    }
    __syncthreads();

    if (tid < 166) {
        int ty;
        float p, ve, ac;
        float* dst;
        if (isCol) {
            ty = tid / 80;
            dst = ws + ty*6400 + (tid % 80)*80;  // HT[ty][s*][.]
            p = ve = ac = 0.f;
        } else {
            int g = tid - 160;                   // g = ty*3 + j
            ty = g / 3;
            int j = g % 3;
            dst = ws + 12800 + g*80;             // GT[g][.]
            p  = (j == 0) ? 1.f : 0.f;
            ve = (j == 1) ? 1.f : 0.f;
            ac = (j == 2) ? 1.f : 0.f;
        }
        for (int t = 0; t < 80; ++t) {
            float4 K4 = ktbl[ty][t];
            float k  = isCol ? ks[t*160 + tid] : 0.f;
            float u  = fmaf(K4.x, p, fmaf(K4.y, ve, fmaf(K4.z, ac, k)));
            float pn = fmaf(DT3, u, fmaf(DT2, ac, fmaf(DT, ve, p)));
            float vn = fmaf(DT2, u, fmaf(DT,  ac, ve));
            ac = fmaf(DT, u, ac);
            p = pn; ve = vn;
            dst[t] = p;                          // plan_t = position of x_{t+1}
        }
    }
}

// ---------------------------------------------------------------------------
// Kernel 2: apply the basis. Block = 256 threads = 4 waves; lane = batch
// (64 batches/block). blockIdx -> (batch group, t-half); wave w covers
// t in [th*40 + w*10, +10), all 3 axes, 10 accumulators.
// Targets staged in LDS as [s*3+a][batch] (conflict-free both ways).
// H^T/G^T reads are wave-uniform -> scalar loads, broadcast.
// ---------------------------------------------------------------------------
__global__ __launch_bounds__(256, 1) void lqr_apply_kernel(
        const float* __restrict__ ego,   // (8192, 9)
        const float* __restrict__ ap,    // (8192, 6, 80, 3)
        const float* __restrict__ ws,
        float* __restrict__ out) {       // (8192, 80, 3)
    __shared__ float sm[240 * 64];       // 61440 B
    const int tid = threadIdx.x;
    const int bg = blockIdx.x >> 1, th = blockIdx.x & 1;
    const int b0 = bg * 64;

    // ---- stage targets: lane = batch, walk 60 float4s per batch ----
    for (int i = tid; i < 64 * 60; i += 256) {
        int bb = i & 63, c = i >> 6;
        float4 v = *(const float4*)(ap + (size_t)(b0 + bb) * 1440 + 1200 + c * 4);
        int f = c * 4;
        sm[(f+0)*64 + bb] = v.x;
        sm[(f+1)*64 + bb] = v.y;
        sm[(f+2)*64 + bb] = v.z;
        sm[(f+3)*64 + bb] = v.w;
    }
    __syncthreads();

    const int lane = tid & 63;
    const int wid  = __builtin_amdgcn_readfirstlane(tid >> 6);
    const int t0   = th * 40 + wid * 10;
    const int b    = b0 + lane;

    float x0p[3], x0v[3], x0a[3];
    #pragma unroll
    for (int a = 0; a < 3; ++a) {
        x0p[a] = ego[b*9 + a];
        x0v[a] = ego[b*9 + 3 + a];
        x0a[a] = ego[b*9 + 6 + a];
    }

    #pragma unroll
    for (int a = 0; a < 3; ++a) {
        const int ty = (a == 2) ? 1 : 0;
        const float* HT = ws + ty * 6400;          // [s][t]
        const float* GT = ws + 12800 + ty * 240;   // [j][t]
        float acc[10];
        #pragma unroll
        for (int i = 0; i < 10; ++i)
            acc[i] = fmaf(GT[t0+i], x0p[a],
                     fmaf(GT[80+t0+i], x0v[a], GT[160+t0+i] * x0a[a]));
        for (int s = 0; s < 80; ++s) {
            float xv = sm[(s*3 + a)*64 + lane];
            const float* Hrow = HT + s*80 + t0;    // wave-uniform -> s_load
            #pragma unroll
            for (int i = 0; i < 10; ++i)
                acc[i] = fmaf(Hrow[i], xv, acc[i]);
        }
        #pragma unroll
        for (int i = 0; i < 10; ++i)
            out[(size_t)b*240 + (t0+i)*3 + a] = acc[i];
    }
}

extern "C" void kernel_launch(void* const* d_in, const int* in_sizes, int n_in,
                              void* d_out, int out_size, void* d_ws, size_t ws_size,
                              hipStream_t stream) {
    const float* ego = (const float*)d_in[0];   // (8192, 9)
    const float* ap  = (const float*)d_in[1];   // (8192, 6, 80, 3)
    float*       out = (float*)d_out;           // (8192, 80, 3)
    float*       ws  = (float*)d_ws;            // 13280 floats = 53120 B

    lqr_basis_kernel<<<1, 192, 0, stream>>>(ws);
    lqr_apply_kernel<<<256, 256, 0, stream>>>(ego, ap, ws, out);
}

// Round 3
// 20.087 us; speedup vs baseline: 2.4673x; 2.4673x over previous
//
#include <hip/hip_runtime.h>

#define DT   0.1f
#define DT2  0.01f
#define DT3  0.001f

// ---------------------------------------------------------------------------
// The 9-state/3-control LQR decouples per axis into a 3-state (p,v,a | jerk)
// problem; axes 0,1 share weights (type 0), axis 2 = yaw (type 1). The
// backward Riccati table (Qxu, 1/Quu, K per step) is batch-independent AND
// input-independent -> computed at COMPILE TIME in double precision.
// ---------------------------------------------------------------------------
struct alignas(16) F4c { float x, y, z, w; };
struct TblData { F4c q[81][2]; F4c k[81][2]; };   // q={Qxu0,Qxu1,Qxu2,m}, k={K,0}

constexpr TblData build_tbl() {
    TblData T{};
    for (int ty = 0; ty < 2; ++ty) {
        const double dt = 0.1, dt2 = 0.01, dt3 = 0.001;
        const double cxp = ty ? 10.0 : 1.0;   // YAW_W vs 1
        const double cxv = ty ? 1.0 : 0.0;    // YAW_VEL_W vs 0
        double v00=0, v01=0, v02=0, v11=0, v12=0, v22=0;   // V symmetric
        for (int t = 80; t >= 0; --t) {
            const double on = (t >= 1) ? 1.0 : 0.0;        // C[0] == 0
            double Vb0 = v00*dt3 + v01*dt2 + v02*dt;
            double Vb1 = v01*dt3 + v11*dt2 + v12*dt;
            double Vb2 = v02*dt3 + v12*dt2 + v22*dt;
            double Quu = on*0.1 + dt3*Vb0 + dt2*Vb1 + dt*Vb2;
            double Qxu0 = Vb0;
            double Qxu1 = dt*Vb0 + Vb1;
            double Qxu2 = dt2*Vb0 + dt*Vb1 + Vb2;
            double M01 = dt*v00 + v01;
            double M02 = dt2*v00 + dt*v01 + v02;
            double M11 = dt*v01 + v11;
            double M12 = dt2*v01 + dt*v11 + v12;
            double M22 = dt2*v02 + dt*v12 + v22;
            double Q00 = on*cxp + v00;
            double Q01 = M01;
            double Q02 = M02;
            double Q11 = on*cxv + dt*M01 + M11;
            double Q12 = dt*M02 + M12;
            double Q22 = on*1.0 + dt2*M02 + dt*M12 + M22;
            double m = -1.0 / Quu;
            T.q[t][ty] = F4c{(float)Qxu0, (float)Qxu1, (float)Qxu2, (float)m};
            T.k[t][ty] = F4c{(float)(Qxu0*m), (float)(Qxu1*m), (float)(Qxu2*m), 0.f};
            v00 = Q00 + m*Qxu0*Qxu0;            // Vn = Qxx + m*Qxu*Qxu^T
            v01 = Q01 + m*Qxu0*Qxu1;            // (Qux + Quu*K == 0)
            v02 = Q02 + m*Qxu0*Qxu2;
            v11 = Q11 + m*Qxu1*Qxu1;
            v12 = Q12 + m*Qxu1*Qxu2;
            v22 = Q22 + m*Qxu2*Qxu2;
        }
    }
    return T;
}
__device__ constexpr TblData g_tbl = build_tbl();

// ---------------------------------------------------------------------------
// Single fused kernel. Block = 96 threads = 32 batches x 3 axes; grid = 256.
// Targets (80x3 floats / batch, contiguous 960 B) staged coalesced into LDS.
// Backward v-recursion stores k_t into the target slot it just consumed
// (k_t -> slot t-1, k_0 -> slot 79). Forward rollout reads k and overwrites
// the same slot with p_t; final coalesced float4 writeback remaps slots.
// LDS row stride 244 floats: 16B-aligned, 244%32=20 -> ~2.7-way bank aliasing.
// ---------------------------------------------------------------------------
#define BPB 32
#define RS  244
#define NTH 96

__global__ __launch_bounds__(NTH) void lqr_fused_kernel(
        const float* __restrict__ ego,   // (8192, 9)
        const float* __restrict__ ap,    // (8192, 6, 80, 3)
        float* __restrict__ out) {       // (8192, 80, 3)
    __shared__ float sm[BPB * RS];       // 31232 B
    const int tid = threadIdx.x;
    const int b0 = blockIdx.x * BPB;

    // ---- stage targets: batch-major, fully coalesced float4 ----
    float4* s4 = (float4*)sm;
    for (int i = tid; i < BPB * 60; i += NTH) {
        int bb = i / 60, c = i - bb * 60;
        const float4* src = (const float4*)(ap + (size_t)(b0 + bb) * 1440 + 1200);
        s4[bb * (RS / 4) + c] = src[c];
    }
    __syncthreads();

    const int bloc = tid / 3;
    const int axis = tid - bloc * 3;
    const int b    = b0 + bloc;
    const int ty   = (axis == 2) ? 1 : 0;
    const float wp = (axis == 2) ? 10.f : 1.f;
    float* row = sm + bloc * RS;

    // ---- backward pass: v-recursion; k_t -> freed slot t-1 ----
    float v0 = 0.f, v1 = 0.f, v2 = 0.f;
    for (int t = 80; t >= 1; --t) {
        F4c A = g_tbl.q[t][ty];
        int   s  = (t - 1) * 3 + axis;
        float c  = -wp * row[s];
        float a1 = fmaf(DT, v0, v1);
        float a2 = fmaf(DT, a1, v2);
        float k  = DT * a2 * A.w;
        v0 = (c + v0) + A.x * k;
        v1 = a1 + A.y * k;
        v2 = a2 + A.z * k;
        row[s] = k;
    }
    {   // t = 0: C==0, only k_0 needed; park at slot 79 (k_80 never used)
        F4c A = g_tbl.q[0][ty];
        float a1 = fmaf(DT, v0, v1);
        float a2 = fmaf(DT, a1, v2);
        row[79 * 3 + axis] = DT * a2 * A.w;
    }

    // ---- forward rollout: read k_t, overwrite slot with p_t ----
    float p  = ego[b * 9 + axis];
    float ve = ego[b * 9 + 3 + axis];
    float ac = ego[b * 9 + 6 + axis];
    for (int t = 0; t < 80; ++t) {
        F4c K = g_tbl.k[t][ty];
        int slot = ((t == 0) ? 79 : (t - 1)) * 3 + axis;
        float kk = row[slot];
        float u  = fmaf(K.x, p, fmaf(K.y, ve, fmaf(K.z, ac, kk)));
        float pn = fmaf(DT3, u, fmaf(DT2, ac, fmaf(DT, ve, p)));
        float vn = fmaf(DT2, u, fmaf(DT, ac, ve));
        ac = fmaf(DT, u, ac);
        p = pn; ve = vn;
        row[slot] = p;                    // p_t parked where k_t lived
    }
    __syncthreads();

    // ---- coalesced writeback: out[b][t][a] <- slot ((t?t-1:79)*3+a) ----
    for (int i = tid; i < BPB * 60; i += NTH) {
        int bb = i / 60, c = i - bb * 60;
        float vals[4];
        #pragma unroll
        for (int e = 0; e < 4; ++e) {
            int f = 4 * c + e;            // f = t*3 + a
            int t = f / 3, a = f - t * 3;
            int slot = ((t == 0) ? 79 : (t - 1)) * 3 + a;
            vals[e] = sm[bb * RS + slot];
        }
        *(float4*)(out + (size_t)(b0 + bb) * 240 + 4 * c) =
            make_float4(vals[0], vals[1], vals[2], vals[3]);
    }
}

extern "C" void kernel_launch(void* const* d_in, const int* in_sizes, int n_in,
                              void* d_out, int out_size, void* d_ws, size_t ws_size,
                              hipStream_t stream) {
    const float* ego = (const float*)d_in[0];   // (8192, 9)
    const float* ap  = (const float*)d_in[1];   // (8192, 6, 80, 3)
    float*       out = (float*)d_out;           // (8192, 80, 3)
    lqr_fused_kernel<<<8192 / BPB, NTH, 0, stream>>>(ego, ap, out);
}